// Round 2
// baseline (123.762 us; speedup 1.0000x reference)
//
#include <hip/hip_runtime.h>
#include <stdint.h>
#include <stddef.h>

#define S_LEN 2048
#define DMODEL 1024
#define NHEAD 16
#define HDIM 64
#define WINSZ 256
#define MROWS 4096
#define NQKV 3072

typedef __bf16 bf16x8 __attribute__((ext_vector_type(8)));
typedef float f32x4 __attribute__((ext_vector_type(4)));
typedef unsigned short us4 __attribute__((ext_vector_type(4)));
typedef unsigned short us8 __attribute__((ext_vector_type(8)));

__device__ __forceinline__ unsigned short f2b(float f) {
  union { float f; unsigned u; } v; v.f = f;
  unsigned u = v.u;
  unsigned r = (u + 0x7FFFu + ((u >> 16) & 1u)) >> 16;
  return (unsigned short)r;
}
__device__ __forceinline__ void storev(float* p, float v) { *p = v; }
__device__ __forceinline__ void storev(unsigned short* p, float v) { *p = f2b(v); }

__device__ __forceinline__ void gload_lds16(const unsigned short* g, unsigned short* l) {
  __builtin_amdgcn_global_load_lds(
      (const __attribute__((address_space(1))) unsigned int*)g,
      (__attribute__((address_space(3))) unsigned int*)l, 16, 0, 0);
}

// ---------------- prep kernels ----------------

__global__ void cast_x_kernel(const float* __restrict__ x, unsigned short* __restrict__ xb) {
  int i = (blockIdx.x * blockDim.x + threadIdx.x) * 4;
  float4 v = *reinterpret_cast<const float4*>(x + i);
  us4 o;
  o[0] = f2b(v.x); o[1] = f2b(v.y); o[2] = f2b(v.z); o[3] = f2b(v.w);
  *reinterpret_cast<us4*>(xb + i) = o;
}

// W: [1024][1024] f32 row-major (k rows, n cols). Wt: [n][k] bf16.
__global__ void transpose_cast_kernel(const float* __restrict__ W, unsigned short* __restrict__ Wt) {
  __shared__ float tile[32][33];
  int n0 = blockIdx.x * 32, k0 = blockIdx.y * 32;
  int tx = threadIdx.x, ty = threadIdx.y;
#pragma unroll
  for (int i = 0; i < 32; i += 8)
    tile[ty + i][tx] = W[(size_t)(k0 + ty + i) * DMODEL + n0 + tx];
  __syncthreads();
#pragma unroll
  for (int i = 0; i < 32; i += 8)
    Wt[(size_t)(n0 + ty + i) * DMODEL + k0 + tx] = f2b(tile[tx][ty + i]);
}

__global__ void pack_bias_kernel(const float* __restrict__ bq, const float* __restrict__ bk,
                                 const float* __restrict__ bv, float* __restrict__ bqkv) {
  int i = blockIdx.x * blockDim.x + threadIdx.x;
  if (i < DMODEL) {
    bqkv[i] = bq[i];
    bqkv[DMODEL + i] = bk[i];
    bqkv[2 * DMODEL + i] = bv[i];
  }
}

// ---------------- GEMM (m97 structure): C[M][N] = A[M][K] * Bt[N][K]^T + bias --------
// BM=128 x BN tile, 256 threads (4 waves, 2x2). Linear LDS [row][64],
// global_load_lds width-16 staging, 16x16x32 bf16 MFMA.

template <int BN, typename OutT>
__global__ __launch_bounds__(256) void gemm_lds_kernel(
    const unsigned short* __restrict__ A, const unsigned short* __restrict__ Bt,
    const float* __restrict__ bias, OutT* __restrict__ C, int N, int K) {
  constexpr int BM = 128;
  constexpr int FN = BN / 32;  // N-frags per wave
  __shared__ unsigned short As[BM * 64];
  __shared__ unsigned short Bs[BN * 64];
  const int tid = threadIdx.x;
  const int m0 = blockIdx.y * BM, n0 = blockIdx.x * BN;
  const int w = tid >> 6, l = tid & 63;
  const int wm = (w >> 1) * 64, wn = (w & 1) * (BN / 2);
  const int lr = l & 15, lg = l >> 4;
  const int srow = tid >> 3, scol = (tid & 7) * 8;  // staging row/col (per 32-row round)

  f32x4 acc[4][FN];
#pragma unroll
  for (int i = 0; i < 4; i++)
#pragma unroll
    for (int j = 0; j < FN; j++) acc[i][j] = (f32x4){0.f, 0.f, 0.f, 0.f};

  const unsigned short* ap = A + (size_t)(m0 + srow) * K + scol;
  const unsigned short* bp = Bt + (size_t)(n0 + srow) * K + scol;

  for (int k0 = 0; k0 < K; k0 += 64) {
    __syncthreads();
#pragma unroll
    for (int r = 0; r < BM / 32; r++)
      gload_lds16(ap + (size_t)r * 32 * K + k0, &As[(r * 32 + srow) * 64 + scol]);
#pragma unroll
    for (int r = 0; r < BN / 32; r++)
      gload_lds16(bp + (size_t)r * 32 * K + k0, &Bs[(r * 32 + srow) * 64 + scol]);
    __syncthreads();
#pragma unroll
    for (int kk = 0; kk < 64; kk += 32) {
      bf16x8 a[4], b[FN];
#pragma unroll
      for (int f = 0; f < 4; f++)
        a[f] = *reinterpret_cast<const bf16x8*>(&As[(wm + f * 16 + lr) * 64 + kk + lg * 8]);
#pragma unroll
      for (int j = 0; j < FN; j++)
        b[j] = *reinterpret_cast<const bf16x8*>(&Bs[(wn + j * 16 + lr) * 64 + kk + lg * 8]);
#pragma unroll
      for (int i = 0; i < 4; i++)
#pragma unroll
        for (int j = 0; j < FN; j++)
          acc[i][j] = __builtin_amdgcn_mfma_f32_16x16x32_bf16(a[i], b[j], acc[i][j], 0, 0, 0);
    }
  }

#pragma unroll
  for (int i = 0; i < 4; i++) {
    int row = m0 + wm + i * 16 + lg * 4;
#pragma unroll
    for (int j = 0; j < FN; j++) {
      int col = n0 + wn + j * 16 + lr;
      float bsv = bias[col];
#pragma unroll
      for (int r = 0; r < 4; r++) {
        float vv = acc[i][j][r] + bsv;
        storev(&C[(size_t)(row + r) * N + col], vv);
      }
    }
  }
}

// ---------------- windowed flash attention ----------------
// Block: (tile, h, b). 4 waves x 16 q-rows = 64 rows. 5 key chunks of 64.

__global__ __launch_bounds__(256) void attn_kernel(const unsigned short* __restrict__ qkv,
                                                   unsigned short* __restrict__ attnb) {
  __shared__ unsigned short Ks[64 * 72];   // K chunk, row j, col d
  __shared__ unsigned short Vt[64 * 72];   // V chunk transposed: row d, col j
  __shared__ unsigned short Ps[4][16 * 72];// per-wave P tile, row q, col j

  const int tid = threadIdx.x;
  const int i0 = blockIdx.x * 64;
  const int h = blockIdx.y;
  const int b = blockIdx.z;
  const int w = tid >> 6, l = tid & 63;
  const int lr = l & 15, lg = l >> 4;
  const size_t rowb = (size_t)b * S_LEN;

  const unsigned short* qptr = qkv + (rowb + i0 + w * 16 + lr) * NQKV + h * HDIM;
  bf16x8 qa[2];
  qa[0] = *reinterpret_cast<const bf16x8*>(qptr + lg * 8);
  qa[1] = *reinterpret_cast<const bf16x8*>(qptr + 32 + lg * 8);

  f32x4 accO[4];
#pragma unroll
  for (int f = 0; f < 4; f++) accO[f] = (f32x4){0.f, 0.f, 0.f, 0.f};
  float Mv[4], Lv[4];
#pragma unroll
  for (int r = 0; r < 4; r++) { Mv[r] = -1e30f; Lv[r] = 0.f; }

  for (int c = 0; c < 5; c++) {
    int j0c = i0 - WINSZ + c * 64;
    if (j0c + 63 < 0) continue;  // uniform across block
    __syncthreads();
    {
      int d4 = (tid & 15) * 4;
      int jl0 = tid >> 4;
#pragma unroll
      for (int it = 0; it < 4; it++) {
        int jl = jl0 + it * 16;
        int jg = j0c + jl;
        us4 kv = (us4){0, 0, 0, 0}, vv = (us4){0, 0, 0, 0};
        if (jg >= 0) {
          const unsigned short* kp = qkv + (rowb + jg) * NQKV + DMODEL + h * HDIM + d4;
          kv = *reinterpret_cast<const us4*>(kp);
          vv = *reinterpret_cast<const us4*>(kp + DMODEL);
        }
        *reinterpret_cast<us4*>(&Ks[jl * 72 + d4]) = kv;
        Vt[(d4 + 0) * 72 + jl] = vv[0];
        Vt[(d4 + 1) * 72 + jl] = vv[1];
        Vt[(d4 + 2) * 72 + jl] = vv[2];
        Vt[(d4 + 3) * 72 + jl] = vv[3];
      }
    }
    __syncthreads();

    f32x4 sa[4];
#pragma unroll
    for (int f = 0; f < 4; f++) sa[f] = (f32x4){0.f, 0.f, 0.f, 0.f};
#pragma unroll
    for (int f = 0; f < 4; f++) {
      bf16x8 k0v = *reinterpret_cast<const bf16x8*>(&Ks[(f * 16 + lr) * 72 + lg * 8]);
      bf16x8 k1v = *reinterpret_cast<const bf16x8*>(&Ks[(f * 16 + lr) * 72 + 32 + lg * 8]);
      sa[f] = __builtin_amdgcn_mfma_f32_16x16x32_bf16(qa[0], k0v, sa[f], 0, 0, 0);
      sa[f] = __builtin_amdgcn_mfma_f32_16x16x32_bf16(qa[1], k1v, sa[f], 0, 0, 0);
    }
#pragma unroll
    for (int f = 0; f < 4; f++) {
      int jg = j0c + f * 16 + lr;
#pragma unroll
      for (int r = 0; r < 4; r++) {
        int irow = i0 + w * 16 + lg * 4 + r;
        float s = sa[f][r] * 0.125f;
        bool ok = (jg >= 0) && (jg <= irow) && (jg >= irow - WINSZ);
        sa[f][r] = ok ? s : -1e30f;
      }
    }
    float pm[4];
#pragma unroll
    for (int r = 0; r < 4; r++) {
      float m = fmaxf(fmaxf(sa[0][r], sa[1][r]), fmaxf(sa[2][r], sa[3][r]));
#pragma unroll
      for (int off = 1; off < 16; off <<= 1) m = fmaxf(m, __shfl_xor(m, off));
      pm[r] = m;
    }
#pragma unroll
    for (int r = 0; r < 4; r++) {
      float Mn = fmaxf(Mv[r], pm[r]);
      float sc = __expf(Mv[r] - Mn);
      Mv[r] = Mn;
      Lv[r] *= sc;
#pragma unroll
      for (int f = 0; f < 4; f++) accO[f][r] *= sc;
    }
    float rs[4] = {0.f, 0.f, 0.f, 0.f};
#pragma unroll
    for (int f = 0; f < 4; f++) {
#pragma unroll
      for (int r = 0; r < 4; r++) {
        float p = __expf(sa[f][r] - Mv[r]);
        rs[r] += p;
        Ps[w][(lg * 4 + r) * 72 + f * 16 + lr] = f2b(p);
      }
    }
#pragma unroll
    for (int r = 0; r < 4; r++) {
      float s = rs[r];
#pragma unroll
      for (int off = 1; off < 16; off <<= 1) s += __shfl_xor(s, off);
      Lv[r] += s;
    }
    bf16x8 pa0 = *reinterpret_cast<const bf16x8*>(&Ps[w][lr * 72 + lg * 8]);
    bf16x8 pa1 = *reinterpret_cast<const bf16x8*>(&Ps[w][lr * 72 + 32 + lg * 8]);
#pragma unroll
    for (int f = 0; f < 4; f++) {
      bf16x8 v0 = *reinterpret_cast<const bf16x8*>(&Vt[(f * 16 + lr) * 72 + lg * 8]);
      bf16x8 v1 = *reinterpret_cast<const bf16x8*>(&Vt[(f * 16 + lr) * 72 + 32 + lg * 8]);
      accO[f] = __builtin_amdgcn_mfma_f32_16x16x32_bf16(pa0, v0, accO[f], 0, 0, 0);
      accO[f] = __builtin_amdgcn_mfma_f32_16x16x32_bf16(pa1, v1, accO[f], 0, 0, 0);
    }
  }

#pragma unroll
  for (int f = 0; f < 4; f++) {
#pragma unroll
    for (int r = 0; r < 4; r++) {
      float o = accO[f][r] / Lv[r];
      int row = i0 + w * 16 + lg * 4 + r;
      attnb[(rowb + row) * DMODEL + h * HDIM + f * 16 + lr] = f2b(o);
    }
  }
}

// ---------------- launch ----------------

extern "C" void kernel_launch(void* const* d_in, const int* in_sizes, int n_in,
                              void* d_out, int out_size, void* d_ws, size_t ws_size,
                              hipStream_t stream) {
  const float* x = (const float*)d_in[0];
  const float* Wq = (const float*)d_in[1];
  const float* bq = (const float*)d_in[2];
  const float* Wk = (const float*)d_in[3];
  const float* bk = (const float*)d_in[4];
  const float* Wv = (const float*)d_in[5];
  const float* bv = (const float*)d_in[6];
  const float* Wo = (const float*)d_in[7];
  const float* bo = (const float*)d_in[8];
  float* out = (float*)d_out;

  unsigned short* xb = (unsigned short*)d_ws;                       // 4096*1024
  unsigned short* WqkvT = xb + (size_t)MROWS * DMODEL;              // 3*1024*1024
  unsigned short* WoT = WqkvT + (size_t)3 * DMODEL * DMODEL;        // 1024*1024
  unsigned short* QKV = WoT + (size_t)DMODEL * DMODEL;              // 4096*3072
  unsigned short* attnb = QKV + (size_t)MROWS * NQKV;               // 4096*1024
  float* bqkv = (float*)(attnb + (size_t)MROWS * DMODEL);           // 3072 f32

  cast_x_kernel<<<4096, 256, 0, stream>>>(x, xb);
  dim3 tb(32, 8);
  transpose_cast_kernel<<<dim3(32, 32), tb, 0, stream>>>(Wq, WqkvT);
  transpose_cast_kernel<<<dim3(32, 32), tb, 0, stream>>>(Wk, WqkvT + (size_t)DMODEL * DMODEL);
  transpose_cast_kernel<<<dim3(32, 32), tb, 0, stream>>>(Wv, WqkvT + (size_t)2 * DMODEL * DMODEL);
  transpose_cast_kernel<<<dim3(32, 32), tb, 0, stream>>>(Wo, WoT);
  pack_bias_kernel<<<4, 256, 0, stream>>>(bq, bk, bv, bqkv);

  gemm_lds_kernel<128, unsigned short><<<dim3(NQKV / 128, MROWS / 128), 256, 0, stream>>>(
      xb, WqkvT, bqkv, QKV, NQKV, DMODEL);

  attn_kernel<<<dim3(S_LEN / 64, NHEAD, 2), 256, 0, stream>>>(QKV, attnb);

  gemm_lds_kernel<64, float><<<dim3(DMODEL / 64, MROWS / 128), 256, 0, stream>>>(
      attnb, WoT, bo, out, DMODEL, DMODEL);
}

// Round 3
// 114.265 us; speedup vs baseline: 1.0831x; 1.0831x over previous
//
#include <hip/hip_runtime.h>
#include <stdint.h>
#include <stddef.h>

#define S_LEN 2048
#define DMODEL 1024
#define NHEAD 16
#define HDIM 64
#define WINSZ 256
#define MROWS 4096
#define NQKV 3072

typedef __bf16 bf16x8 __attribute__((ext_vector_type(8)));
typedef float f32x4 __attribute__((ext_vector_type(4)));
typedef unsigned short us4 __attribute__((ext_vector_type(4)));
typedef unsigned short us8 __attribute__((ext_vector_type(8)));

#define MFMA16(a, b, c) __builtin_amdgcn_mfma_f32_16x16x32_bf16((a), (b), (c), 0, 0, 0)

__device__ __forceinline__ unsigned short f2b(float f) {
  union { float f; unsigned u; } v; v.f = f;
  unsigned u = v.u;
  unsigned r = (u + 0x7FFFu + ((u >> 16) & 1u)) >> 16;
  return (unsigned short)r;
}
__device__ __forceinline__ void storev(float* p, float v) { *p = v; }
__device__ __forceinline__ void storev(unsigned short* p, float v) { *p = f2b(v); }

__device__ __forceinline__ void gload_lds16(const unsigned short* g, unsigned short* l) {
  __builtin_amdgcn_global_load_lds(
      (const __attribute__((address_space(1))) unsigned int*)g,
      (__attribute__((address_space(3))) unsigned int*)l, 16, 0, 0);
}

// ---------------- prep kernels ----------------

__global__ void cast_x_kernel(const float* __restrict__ x, unsigned short* __restrict__ xb) {
  int i = (blockIdx.x * blockDim.x + threadIdx.x) * 4;
  float4 v = *reinterpret_cast<const float4*>(x + i);
  us4 o;
  o[0] = f2b(v.x); o[1] = f2b(v.y); o[2] = f2b(v.z); o[3] = f2b(v.w);
  *reinterpret_cast<us4*>(xb + i) = o;
}

__global__ void transpose_cast_kernel(const float* __restrict__ W, unsigned short* __restrict__ Wt) {
  __shared__ float tile[32][33];
  int n0 = blockIdx.x * 32, k0 = blockIdx.y * 32;
  int tx = threadIdx.x, ty = threadIdx.y;
#pragma unroll
  for (int i = 0; i < 32; i += 8)
    tile[ty + i][tx] = W[(size_t)(k0 + ty + i) * DMODEL + n0 + tx];
  __syncthreads();
#pragma unroll
  for (int i = 0; i < 32; i += 8)
    Wt[(size_t)(n0 + ty + i) * DMODEL + k0 + tx] = f2b(tile[tx][ty + i]);
}

__global__ void pack_bias_kernel(const float* __restrict__ bq, const float* __restrict__ bk,
                                 const float* __restrict__ bv, float* __restrict__ bqkv) {
  int i = blockIdx.x * blockDim.x + threadIdx.x;
  if (i < DMODEL) {
    bqkv[i] = bq[i];
    bqkv[DMODEL + i] = bk[i];
    bqkv[2 * DMODEL + i] = bv[i];
  }
}

// ---------------- 8-phase 256x256 GEMM (QKV projection) ----------------
// C[M][N] = A[M][K](bf16) * Bt[N][K]^T + bias, out bf16.
// 512 threads = 8 waves (2M x 4N), BK=64, LDS 128 KiB, st_16x32 swizzle,
// counted vmcnt(2) at tile boundary, setprio around MFMA clusters.

__global__ __launch_bounds__(512, 2) void gemm8p_kernel(
    const unsigned short* __restrict__ A, const unsigned short* __restrict__ Bt,
    const float* __restrict__ bias, unsigned short* __restrict__ C, int N, int K) {
  // layout: [dbuf 2][kk-block 2][row 256][col 32 elems]
  __shared__ unsigned short As[2 * 2 * 256 * 32];
  __shared__ unsigned short Bs[2 * 2 * 256 * 32];
  const int tid = threadIdx.x;
  const int m0 = blockIdx.y * 256, n0 = blockIdx.x * 256;
  const int wid = tid >> 6, l = tid & 63;
  const int wm = wid >> 2, wn = wid & 3;           // 2 x 4 wave grid
  const int lr = l & 15, lg = l >> 4;
  const int srow = tid >> 2;                        // staging row 0..127
  const int scol_lin = (tid & 3) * 8;               // linear LDS col (elems)
  const int scol_e = scol_lin ^ (((srow >> 3) & 1) << 4);  // pre-swizzled global col
  const int rflip = ((lr >> 3) & 1) << 4;           // read-side swizzle (elems)
  const int NT = K >> 6;                            // 16

  f32x4 acc[8][4];
#pragma unroll
  for (int i = 0; i < 8; i++)
#pragma unroll
    for (int j = 0; j < 4; j++) acc[i][j] = (f32x4){0.f, 0.f, 0.f, 0.f};

  auto stA = [&](int q, int h, int kt) {
#pragma unroll
    for (int cb = 0; cb < 2; cb++)
      gload_lds16(A + (size_t)(m0 + h * 128 + srow) * K + kt * 64 + cb * 32 + scol_e,
                  &As[(((q << 1) + cb) * 256 + h * 128 + srow) * 32 + scol_lin]);
  };
  auto stB = [&](int q, int h, int kt) {
#pragma unroll
    for (int cb = 0; cb < 2; cb++)
      gload_lds16(Bt + (size_t)(n0 + h * 128 + srow) * K + kt * 64 + cb * 32 + scol_e,
                  &Bs[(((q << 1) + cb) * 256 + h * 128 + srow) * 32 + scol_lin]);
  };

  // prologue: tile0 fully (buf0) + B0(tile1) (buf1); drain all but newest half.
  stB(0, 0, 0); stB(0, 1, 0); stA(0, 0, 0); stA(0, 1, 0); stB(1, 0, 1);
  asm volatile("s_waitcnt vmcnt(2)" ::: "memory");
  __builtin_amdgcn_s_barrier();

  bf16x8 a[4][2], b01[2][2], b23[2][2];
  const int aBase = (wm * 128 + lr) * 32 + ((lg * 8) ^ rflip);
  const int bBase = (wn * 64 + lr) * 32 + ((lg * 8) ^ rflip);

#pragma unroll 1
  for (int t = 0; t < NT; t++) {
    const int p = t & 1, q = p ^ 1;
    const int ap = p * 16384, bp = p * 16384;  // dbuf byte^... element offsets (2*256*32)

    // ===== phase 0: read a(0..3), b(0..1); stage B1(t+1); MFMA q0 =====
#pragma unroll
    for (int i = 0; i < 4; i++)
#pragma unroll
      for (int kk = 0; kk < 2; kk++)
        a[i][kk] = *reinterpret_cast<const bf16x8*>(&As[ap + kk * 8192 + i * 512 + aBase]);
#pragma unroll
    for (int j = 0; j < 2; j++)
#pragma unroll
      for (int kk = 0; kk < 2; kk++)
        b01[j][kk] = *reinterpret_cast<const bf16x8*>(&Bs[bp + kk * 8192 + j * 512 + bBase]);
    if (t + 1 < NT) stB(q, 1, t + 1);
    __builtin_amdgcn_s_barrier();
    __builtin_amdgcn_s_setprio(1);
#pragma unroll
    for (int i = 0; i < 4; i++)
#pragma unroll
      for (int j = 0; j < 2; j++)
#pragma unroll
        for (int kk = 0; kk < 2; kk++)
          acc[i][j] = MFMA16(a[i][kk], b01[j][kk], acc[i][j]);
    __builtin_amdgcn_s_setprio(0);
    __builtin_amdgcn_s_barrier();

    // ===== phase 1: read b(2..3); stage A0(t+1); MFMA q1 =====
#pragma unroll
    for (int j = 0; j < 2; j++)
#pragma unroll
      for (int kk = 0; kk < 2; kk++)
        b23[j][kk] = *reinterpret_cast<const bf16x8*>(&Bs[bp + kk * 8192 + (j + 2) * 512 + bBase]);
    if (t + 1 < NT) stA(q, 0, t + 1);
    __builtin_amdgcn_s_barrier();
    __builtin_amdgcn_s_setprio(1);
#pragma unroll
    for (int i = 0; i < 4; i++)
#pragma unroll
      for (int j = 0; j < 2; j++)
#pragma unroll
        for (int kk = 0; kk < 2; kk++)
          acc[i][j + 2] = MFMA16(a[i][kk], b23[j][kk], acc[i][j + 2]);
    __builtin_amdgcn_s_setprio(0);
    __builtin_amdgcn_s_barrier();

    // ===== phase 2: read a(4..7); stage A1(t+1); MFMA q2 =====
#pragma unroll
    for (int i = 0; i < 4; i++)
#pragma unroll
      for (int kk = 0; kk < 2; kk++)
        a[i][kk] = *reinterpret_cast<const bf16x8*>(&As[ap + kk * 8192 + (i + 4) * 512 + aBase]);
    if (t + 1 < NT) stA(q, 1, t + 1);
    __builtin_amdgcn_s_barrier();
    __builtin_amdgcn_s_setprio(1);
#pragma unroll
    for (int i = 0; i < 4; i++)
#pragma unroll
      for (int j = 0; j < 2; j++)
#pragma unroll
        for (int kk = 0; kk < 2; kk++)
          acc[i + 4][j] = MFMA16(a[i][kk], b01[j][kk], acc[i + 4][j]);
    __builtin_amdgcn_s_setprio(0);
    __builtin_amdgcn_s_barrier();

    // ===== phase 3: stage B0(t+2); MFMA q3; counted vmcnt; barrier =====
    if (t + 2 < NT) stB(p, 0, t + 2);
    __builtin_amdgcn_s_barrier();
    __builtin_amdgcn_s_setprio(1);
#pragma unroll
    for (int i = 0; i < 4; i++)
#pragma unroll
      for (int j = 0; j < 2; j++)
#pragma unroll
        for (int kk = 0; kk < 2; kk++)
          acc[i + 4][j + 2] = MFMA16(a[i][kk], b23[j][kk], acc[i + 4][j + 2]);
    __builtin_amdgcn_s_setprio(0);
    if (t + 2 < NT) {
      asm volatile("s_waitcnt vmcnt(2)" ::: "memory");
    } else {
      asm volatile("s_waitcnt vmcnt(0)" ::: "memory");
    }
    __builtin_amdgcn_s_barrier();
  }

#pragma unroll
  for (int i = 0; i < 8; i++) {
    int row = m0 + wm * 128 + i * 16 + lg * 4;
#pragma unroll
    for (int j = 0; j < 4; j++) {
      int col = n0 + wn * 64 + j * 16 + lr;
      float bsv = bias[col];
#pragma unroll
      for (int r = 0; r < 4; r++)
        C[(size_t)(row + r) * N + col] = f2b(acc[i][j][r] + bsv);
    }
  }
}

// ---------------- 2-phase double-buffered 128x128 GEMM (output projection) ----
// T3-minimum: issue next-tile global_load_lds BEFORE compute, vmcnt(0)+barrier after.

template <typename OutT>
__global__ __launch_bounds__(256) void gemm2p_kernel(
    const unsigned short* __restrict__ A, const unsigned short* __restrict__ Bt,
    const float* __restrict__ bias, OutT* __restrict__ C, int N, int K) {
  __shared__ unsigned short As[2][128 * 64];
  __shared__ unsigned short Bs[2][128 * 64];
  const int tid = threadIdx.x;
  const int m0 = blockIdx.y * 128, n0 = blockIdx.x * 128;
  const int w = tid >> 6, l = tid & 63;
  const int wm = (w >> 1) * 64, wn = (w & 1) * 64;
  const int lr = l & 15, lg = l >> 4;
  const int srow = tid >> 3, scol = (tid & 7) * 8;  // 32 rows per round
  const int NT = K >> 6;

  f32x4 acc[4][4];
#pragma unroll
  for (int i = 0; i < 4; i++)
#pragma unroll
    for (int j = 0; j < 4; j++) acc[i][j] = (f32x4){0.f, 0.f, 0.f, 0.f};

  auto stage = [&](int buf, int kt) {
#pragma unroll
    for (int r = 0; r < 4; r++) {
      gload_lds16(A + (size_t)(m0 + r * 32 + srow) * K + kt * 64 + scol,
                  &As[buf][(r * 32 + srow) * 64 + scol]);
      gload_lds16(Bt + (size_t)(n0 + r * 32 + srow) * K + kt * 64 + scol,
                  &Bs[buf][(r * 32 + srow) * 64 + scol]);
    }
  };

  stage(0, 0);
  asm volatile("s_waitcnt vmcnt(0)" ::: "memory");
  __builtin_amdgcn_s_barrier();

  int cur = 0;
#pragma unroll 1
  for (int t = 0; t < NT; t++) {
    if (t + 1 < NT) stage(cur ^ 1, t + 1);  // issue first: overlaps with compute below
    bf16x8 a[4][2], b[4][2];
#pragma unroll
    for (int f = 0; f < 4; f++)
#pragma unroll
      for (int kk = 0; kk < 2; kk++) {
        a[f][kk] = *reinterpret_cast<const bf16x8*>(&As[cur][(wm + f * 16 + lr) * 64 + kk * 32 + lg * 8]);
        b[f][kk] = *reinterpret_cast<const bf16x8*>(&Bs[cur][(wn + f * 16 + lr) * 64 + kk * 32 + lg * 8]);
      }
    __builtin_amdgcn_s_setprio(1);
#pragma unroll
    for (int i = 0; i < 4; i++)
#pragma unroll
      for (int j = 0; j < 4; j++)
#pragma unroll
        for (int kk = 0; kk < 2; kk++)
          acc[i][j] = MFMA16(a[i][kk], b[j][kk], acc[i][j]);
    __builtin_amdgcn_s_setprio(0);
    asm volatile("s_waitcnt vmcnt(0)" ::: "memory");
    __builtin_amdgcn_s_barrier();
    cur ^= 1;
  }

#pragma unroll
  for (int i = 0; i < 4; i++) {
    int row = m0 + wm + i * 16 + lg * 4;
#pragma unroll
    for (int j = 0; j < 4; j++) {
      int col = n0 + wn + j * 16 + lr;
      float bsv = bias[col];
#pragma unroll
      for (int r = 0; r < 4; r++)
        storev(&C[(size_t)(row + r) * N + col], acc[i][j][r] + bsv);
    }
  }
}

// ---------------- windowed flash attention ----------------

__global__ __launch_bounds__(256) void attn_kernel(const unsigned short* __restrict__ qkv,
                                                   unsigned short* __restrict__ attnb) {
  __shared__ unsigned short Ks[64 * 72];
  __shared__ unsigned short Vt[64 * 72];
  __shared__ unsigned short Ps[4][16 * 72];

  const int tid = threadIdx.x;
  const int i0 = blockIdx.x * 64;
  const int h = blockIdx.y;
  const int b = blockIdx.z;
  const int w = tid >> 6, l = tid & 63;
  const int lr = l & 15, lg = l >> 4;
  const size_t rowb = (size_t)b * S_LEN;

  const unsigned short* qptr = qkv + (rowb + i0 + w * 16 + lr) * NQKV + h * HDIM;
  bf16x8 qa[2];
  qa[0] = *reinterpret_cast<const bf16x8*>(qptr + lg * 8);
  qa[1] = *reinterpret_cast<const bf16x8*>(qptr + 32 + lg * 8);

  f32x4 accO[4];
#pragma unroll
  for (int f = 0; f < 4; f++) accO[f] = (f32x4){0.f, 0.f, 0.f, 0.f};
  float Mv[4], Lv[4];
#pragma unroll
  for (int r = 0; r < 4; r++) { Mv[r] = -1e30f; Lv[r] = 0.f; }

  for (int c = 0; c < 5; c++) {
    int j0c = i0 - WINSZ + c * 64;
    if (j0c + 63 < 0) continue;
    __syncthreads();
    {
      int d4 = (tid & 15) * 4;
      int jl0 = tid >> 4;
#pragma unroll
      for (int it = 0; it < 4; it++) {
        int jl = jl0 + it * 16;
        int jg = j0c + jl;
        us4 kv = (us4){0, 0, 0, 0}, vv = (us4){0, 0, 0, 0};
        if (jg >= 0) {
          const unsigned short* kp = qkv + (rowb + jg) * NQKV + DMODEL + h * HDIM + d4;
          kv = *reinterpret_cast<const us4*>(kp);
          vv = *reinterpret_cast<const us4*>(kp + DMODEL);
        }
        *reinterpret_cast<us4*>(&Ks[jl * 72 + d4]) = kv;
        Vt[(d4 + 0) * 72 + jl] = vv[0];
        Vt[(d4 + 1) * 72 + jl] = vv[1];
        Vt[(d4 + 2) * 72 + jl] = vv[2];
        Vt[(d4 + 3) * 72 + jl] = vv[3];
      }
    }
    __syncthreads();

    f32x4 sa[4];
#pragma unroll
    for (int f = 0; f < 4; f++) sa[f] = (f32x4){0.f, 0.f, 0.f, 0.f};
#pragma unroll
    for (int f = 0; f < 4; f++) {
      bf16x8 k0v = *reinterpret_cast<const bf16x8*>(&Ks[(f * 16 + lr) * 72 + lg * 8]);
      bf16x8 k1v = *reinterpret_cast<const bf16x8*>(&Ks[(f * 16 + lr) * 72 + 32 + lg * 8]);
      sa[f] = MFMA16(qa[0], k0v, sa[f]);
      sa[f] = MFMA16(qa[1], k1v, sa[f]);
    }
#pragma unroll
    for (int f = 0; f < 4; f++) {
      int jg = j0c + f * 16 + lr;
#pragma unroll
      for (int r = 0; r < 4; r++) {
        int irow = i0 + w * 16 + lg * 4 + r;
        float s = sa[f][r] * 0.125f;
        bool ok = (jg >= 0) && (jg <= irow) && (jg >= irow - WINSZ);
        sa[f][r] = ok ? s : -1e30f;
      }
    }
    float pm[4];
#pragma unroll
    for (int r = 0; r < 4; r++) {
      float m = fmaxf(fmaxf(sa[0][r], sa[1][r]), fmaxf(sa[2][r], sa[3][r]));
#pragma unroll
      for (int off = 1; off < 16; off <<= 1) m = fmaxf(m, __shfl_xor(m, off));
      pm[r] = m;
    }
#pragma unroll
    for (int r = 0; r < 4; r++) {
      float Mn = fmaxf(Mv[r], pm[r]);
      float sc = __expf(Mv[r] - Mn);
      Mv[r] = Mn;
      Lv[r] *= sc;
#pragma unroll
      for (int f = 0; f < 4; f++) accO[f][r] *= sc;
    }
    float rs[4] = {0.f, 0.f, 0.f, 0.f};
#pragma unroll
    for (int f = 0; f < 4; f++) {
#pragma unroll
      for (int r = 0; r < 4; r++) {
        float p = __expf(sa[f][r] - Mv[r]);
        rs[r] += p;
        Ps[w][(lg * 4 + r) * 72 + f * 16 + lr] = f2b(p);
      }
    }
#pragma unroll
    for (int r = 0; r < 4; r++) {
      float s = rs[r];
#pragma unroll
      for (int off = 1; off < 16; off <<= 1) s += __shfl_xor(s, off);
      Lv[r] += s;
    }
    bf16x8 pa0 = *reinterpret_cast<const bf16x8*>(&Ps[w][lr * 72 + lg * 8]);
    bf16x8 pa1 = *reinterpret_cast<const bf16x8*>(&Ps[w][lr * 72 + 32 + lg * 8]);
#pragma unroll
    for (int f = 0; f < 4; f++) {
      bf16x8 v0 = *reinterpret_cast<const bf16x8*>(&Vt[(f * 16 + lr) * 72 + lg * 8]);
      bf16x8 v1 = *reinterpret_cast<const bf16x8*>(&Vt[(f * 16 + lr) * 72 + 32 + lg * 8]);
      accO[f] = MFMA16(pa0, v0, accO[f]);
      accO[f] = MFMA16(pa1, v1, accO[f]);
    }
  }

#pragma unroll
  for (int f = 0; f < 4; f++) {
#pragma unroll
    for (int r = 0; r < 4; r++) {
      float o = accO[f][r] / Lv[r];
      int row = i0 + w * 16 + lg * 4 + r;
      attnb[(rowb + row) * DMODEL + h * HDIM + f * 16 + lr] = f2b(o);
    }
  }
}

// ---------------- launch ----------------

extern "C" void kernel_launch(void* const* d_in, const int* in_sizes, int n_in,
                              void* d_out, int out_size, void* d_ws, size_t ws_size,
                              hipStream_t stream) {
  const float* x = (const float*)d_in[0];
  const float* Wq = (const float*)d_in[1];
  const float* bq = (const float*)d_in[2];
  const float* Wk = (const float*)d_in[3];
  const float* bk = (const float*)d_in[4];
  const float* Wv = (const float*)d_in[5];
  const float* bv = (const float*)d_in[6];
  const float* Wo = (const float*)d_in[7];
  const float* bo = (const float*)d_in[8];
  float* out = (float*)d_out;

  unsigned short* xb = (unsigned short*)d_ws;                       // 4096*1024
  unsigned short* WqkvT = xb + (size_t)MROWS * DMODEL;              // 3*1024*1024
  unsigned short* WoT = WqkvT + (size_t)3 * DMODEL * DMODEL;        // 1024*1024
  unsigned short* QKV = WoT + (size_t)DMODEL * DMODEL;              // 4096*3072
  unsigned short* attnb = QKV + (size_t)MROWS * NQKV;               // 4096*1024
  float* bqkv = (float*)(attnb + (size_t)MROWS * DMODEL);           // 3072 f32

  cast_x_kernel<<<4096, 256, 0, stream>>>(x, xb);
  dim3 tb(32, 8);
  transpose_cast_kernel<<<dim3(32, 32), tb, 0, stream>>>(Wq, WqkvT);
  transpose_cast_kernel<<<dim3(32, 32), tb, 0, stream>>>(Wk, WqkvT + (size_t)DMODEL * DMODEL);
  transpose_cast_kernel<<<dim3(32, 32), tb, 0, stream>>>(Wv, WqkvT + (size_t)2 * DMODEL * DMODEL);
  transpose_cast_kernel<<<dim3(32, 32), tb, 0, stream>>>(Wo, WoT);
  pack_bias_kernel<<<4, 256, 0, stream>>>(bq, bk, bv, bqkv);

  gemm8p_kernel<<<dim3(NQKV / 256, MROWS / 256), 512, 0, stream>>>(
      xb, WqkvT, bqkv, QKV, NQKV, DMODEL);

  attn_kernel<<<dim3(S_LEN / 64, NHEAD, 2), 256, 0, stream>>>(QKV, attnb);

  gemm2p_kernel<float><<<dim3(DMODEL / 128, MROWS / 128), 256, 0, stream>>>(
      attnb, WoT, bo, out, DMODEL, DMODEL);
}

// Round 4
// 104.690 us; speedup vs baseline: 1.1822x; 1.0915x over previous
//
#include <hip/hip_runtime.h>
#include <stdint.h>
#include <stddef.h>

#define S_LEN 2048
#define DMODEL 1024
#define NHEAD 16
#define HDIM 64
#define WINSZ 256
#define MROWS 4096
#define NQKV 3072

typedef __bf16 bf16x8 __attribute__((ext_vector_type(8)));
typedef float f32x4 __attribute__((ext_vector_type(4)));
typedef unsigned short us4 __attribute__((ext_vector_type(4)));
typedef unsigned short us8 __attribute__((ext_vector_type(8)));

#define MFMA16(a, b, c) __builtin_amdgcn_mfma_f32_16x16x32_bf16((a), (b), (c), 0, 0, 0)

__device__ __forceinline__ unsigned short f2b(float f) {
  union { float f; unsigned u; } v; v.f = f;
  unsigned u = v.u;
  unsigned r = (u + 0x7FFFu + ((u >> 16) & 1u)) >> 16;
  return (unsigned short)r;
}
__device__ __forceinline__ void storev(float* p, float v) { *p = v; }
__device__ __forceinline__ void storev(unsigned short* p, float v) { *p = f2b(v); }

__device__ __forceinline__ void gload_lds16(const unsigned short* g, unsigned short* l) {
  __builtin_amdgcn_global_load_lds(
      (const __attribute__((address_space(1))) unsigned int*)g,
      (__attribute__((address_space(3))) unsigned int*)l, 16, 0, 0);
}

// 2-bit LDS swizzle for 32-elem (64B) rows: col bits {3,4} ^= row bits {2,1}.
// bank(row,col)=(row*16+col/2)%32 -> groups 16*row0 + 8*(col4^row1) + 4*(col3^row2)
// -> 8 distinct 4-bank groups over 16 consecutive rows -> 2 lanes/bank (free).
__device__ __forceinline__ int swz(int row) {
  return (((row >> 1) & 1) << 4) | (((row >> 2) & 1) << 3);
}

// ---------------- prep kernels ----------------

__global__ void cast_x_kernel(const float* __restrict__ x, unsigned short* __restrict__ xb) {
  int i = (blockIdx.x * blockDim.x + threadIdx.x) * 4;
  float4 v = *reinterpret_cast<const float4*>(x + i);
  us4 o;
  o[0] = f2b(v.x); o[1] = f2b(v.y); o[2] = f2b(v.z); o[3] = f2b(v.w);
  *reinterpret_cast<us4*>(xb + i) = o;
}

// Batched: z selects which W to transpose+cast.
__global__ void transpose_cast4_kernel(const float* __restrict__ s0, const float* __restrict__ s1,
                                       const float* __restrict__ s2, const float* __restrict__ s3,
                                       unsigned short* __restrict__ d0, unsigned short* __restrict__ d1,
                                       unsigned short* __restrict__ d2, unsigned short* __restrict__ d3) {
  __shared__ float tile[32][33];
  const float* W = (blockIdx.z == 0) ? s0 : (blockIdx.z == 1) ? s1 : (blockIdx.z == 2) ? s2 : s3;
  unsigned short* Wt = (blockIdx.z == 0) ? d0 : (blockIdx.z == 1) ? d1 : (blockIdx.z == 2) ? d2 : d3;
  int n0 = blockIdx.x * 32, k0 = blockIdx.y * 32;
  int tx = threadIdx.x, ty = threadIdx.y;
#pragma unroll
  for (int i = 0; i < 32; i += 8)
    tile[ty + i][tx] = W[(size_t)(k0 + ty + i) * DMODEL + n0 + tx];
  __syncthreads();
#pragma unroll
  for (int i = 0; i < 32; i += 8)
    Wt[(size_t)(n0 + ty + i) * DMODEL + k0 + tx] = f2b(tile[tx][ty + i]);
}

__global__ void pack_bias_kernel(const float* __restrict__ bq, const float* __restrict__ bk,
                                 const float* __restrict__ bv, float* __restrict__ bqkv) {
  int i = blockIdx.x * blockDim.x + threadIdx.x;
  if (i < DMODEL) {
    bqkv[i] = bq[i];
    bqkv[DMODEL + i] = bk[i];
    bqkv[2 * DMODEL + i] = bv[i];
  }
}

// ---------------- 8-phase 256x256 GEMM (QKV projection) ----------------
// 512 threads = 8 waves (2M x 4N), BK=64, LDS 128 KiB [dbuf][kk][256][32],
// 2-bit swizzle, counted vmcnt(2), setprio, chunked XCD block swizzle.

__global__ __launch_bounds__(512, 2) void gemm8p_kernel(
    const unsigned short* __restrict__ A, const unsigned short* __restrict__ Bt,
    const float* __restrict__ bias, unsigned short* __restrict__ C, int N, int K) {
  __shared__ unsigned short As[2 * 2 * 256 * 32];
  __shared__ unsigned short Bs[2 * 2 * 256 * 32];
  const int tid = threadIdx.x;
  // chunked XCD swizzle (gridDim.x % 8 == 0)
  const int cpx = gridDim.x >> 3;
  const int nid = (blockIdx.x & 7) * cpx + (blockIdx.x >> 3);
  const int nbx = N >> 8;
  const int by = nid / nbx, bx = nid - by * nbx;
  const int m0 = by * 256, n0 = bx * 256;
  const int wid = tid >> 6, l = tid & 63;
  const int wm = wid >> 2, wn = wid & 3;
  const int lr = l & 15, lg = l >> 4;
  const int srow = tid >> 2;                        // 0..127
  const int scol_lin = (tid & 3) * 8;
  const int scol_e = scol_lin ^ swz(srow);          // pre-swizzled global col
  const int NT = K >> 6;

  f32x4 acc[8][4];
#pragma unroll
  for (int i = 0; i < 8; i++)
#pragma unroll
    for (int j = 0; j < 4; j++) acc[i][j] = (f32x4){0.f, 0.f, 0.f, 0.f};

  auto stA = [&](int q, int h, int kt) {
#pragma unroll
    for (int cb = 0; cb < 2; cb++)
      gload_lds16(A + (size_t)(m0 + h * 128 + srow) * K + kt * 64 + cb * 32 + scol_e,
                  &As[(((q << 1) + cb) * 256 + h * 128 + srow) * 32 + scol_lin]);
  };
  auto stB = [&](int q, int h, int kt) {
#pragma unroll
    for (int cb = 0; cb < 2; cb++)
      gload_lds16(Bt + (size_t)(n0 + h * 128 + srow) * K + kt * 64 + cb * 32 + scol_e,
                  &Bs[(((q << 1) + cb) * 256 + h * 128 + srow) * 32 + scol_lin]);
  };

  stB(0, 0, 0); stB(0, 1, 0); stA(0, 0, 0); stA(0, 1, 0); stB(1, 0, 1);
  asm volatile("s_waitcnt vmcnt(2)" ::: "memory");
  __builtin_amdgcn_s_barrier();

  bf16x8 a[4][2], b01[2][2], b23[2][2];
  const int cswz = swz(lr);
  const int aBase = (wm * 128 + lr) * 32 + ((lg * 8) ^ cswz);
  const int bBase = (wn * 64 + lr) * 32 + ((lg * 8) ^ cswz);

#pragma unroll 1
  for (int t = 0; t < NT; t++) {
    const int p = t & 1, q = p ^ 1;
    const int ap = p * 16384, bp = p * 16384;

    // phase 0: read a(0..3), b(0..1); stage B1(t+1); MFMA q0
#pragma unroll
    for (int i = 0; i < 4; i++)
#pragma unroll
      for (int kk = 0; kk < 2; kk++)
        a[i][kk] = *reinterpret_cast<const bf16x8*>(&As[ap + kk * 8192 + i * 512 + aBase]);
#pragma unroll
    for (int j = 0; j < 2; j++)
#pragma unroll
      for (int kk = 0; kk < 2; kk++)
        b01[j][kk] = *reinterpret_cast<const bf16x8*>(&Bs[bp + kk * 8192 + j * 512 + bBase]);
    if (t + 1 < NT) stB(q, 1, t + 1);
    __builtin_amdgcn_s_barrier();
    __builtin_amdgcn_s_setprio(1);
#pragma unroll
    for (int i = 0; i < 4; i++)
#pragma unroll
      for (int j = 0; j < 2; j++)
#pragma unroll
        for (int kk = 0; kk < 2; kk++)
          acc[i][j] = MFMA16(a[i][kk], b01[j][kk], acc[i][j]);
    __builtin_amdgcn_s_setprio(0);
    __builtin_amdgcn_s_barrier();

    // phase 1: read b(2..3); stage A0(t+1); MFMA q1
#pragma unroll
    for (int j = 0; j < 2; j++)
#pragma unroll
      for (int kk = 0; kk < 2; kk++)
        b23[j][kk] = *reinterpret_cast<const bf16x8*>(&Bs[bp + kk * 8192 + (j + 2) * 512 + bBase]);
    if (t + 1 < NT) stA(q, 0, t + 1);
    __builtin_amdgcn_s_barrier();
    __builtin_amdgcn_s_setprio(1);
#pragma unroll
    for (int i = 0; i < 4; i++)
#pragma unroll
      for (int j = 0; j < 2; j++)
#pragma unroll
        for (int kk = 0; kk < 2; kk++)
          acc[i][j + 2] = MFMA16(a[i][kk], b23[j][kk], acc[i][j + 2]);
    __builtin_amdgcn_s_setprio(0);
    __builtin_amdgcn_s_barrier();

    // phase 2: read a(4..7); stage A1(t+1); MFMA q2
#pragma unroll
    for (int i = 0; i < 4; i++)
#pragma unroll
      for (int kk = 0; kk < 2; kk++)
        a[i][kk] = *reinterpret_cast<const bf16x8*>(&As[ap + kk * 8192 + (i + 4) * 512 + aBase]);
    if (t + 1 < NT) stA(q, 1, t + 1);
    __builtin_amdgcn_s_barrier();
    __builtin_amdgcn_s_setprio(1);
#pragma unroll
    for (int i = 0; i < 4; i++)
#pragma unroll
      for (int j = 0; j < 2; j++)
#pragma unroll
        for (int kk = 0; kk < 2; kk++)
          acc[i + 4][j] = MFMA16(a[i][kk], b01[j][kk], acc[i + 4][j]);
    __builtin_amdgcn_s_setprio(0);
    __builtin_amdgcn_s_barrier();

    // phase 3: stage B0(t+2); MFMA q3; counted vmcnt
    if (t + 2 < NT) stB(p, 0, t + 2);
    __builtin_amdgcn_s_barrier();
    __builtin_amdgcn_s_setprio(1);
#pragma unroll
    for (int i = 0; i < 4; i++)
#pragma unroll
      for (int j = 0; j < 2; j++)
#pragma unroll
        for (int kk = 0; kk < 2; kk++)
          acc[i + 4][j + 2] = MFMA16(a[i][kk], b23[j][kk], acc[i + 4][j + 2]);
    __builtin_amdgcn_s_setprio(0);
    if (t + 2 < NT) {
      asm volatile("s_waitcnt vmcnt(2)" ::: "memory");
    } else {
      asm volatile("s_waitcnt vmcnt(0)" ::: "memory");
    }
    __builtin_amdgcn_s_barrier();
  }

#pragma unroll
  for (int i = 0; i < 8; i++) {
    int row = m0 + wm * 128 + i * 16 + lg * 4;
#pragma unroll
    for (int j = 0; j < 4; j++) {
      int col = n0 + wn * 64 + j * 16 + lr;
      float bsv = bias[col];
#pragma unroll
      for (int r = 0; r < 4; r++)
        C[(size_t)(row + r) * N + col] = f2b(acc[i][j][r] + bsv);
    }
  }
}

// ---------------- 2-phase 128x64 GEMM (output projection) ----------------
// 256 threads (4 waves 2x2), LDS 48 KiB [dbuf][kk][rows][32] -> 3 blocks/CU,
// 2-bit swizzle, issue-stage-before-compute, vmcnt(0) after MFMA.

template <typename OutT>
__global__ __launch_bounds__(256, 3) void gemm2p_kernel(
    const unsigned short* __restrict__ A, const unsigned short* __restrict__ Bt,
    const float* __restrict__ bias, OutT* __restrict__ C, int N, int K) {
  __shared__ unsigned short As[2 * 2 * 128 * 32];  // 32 KB
  __shared__ unsigned short Bs[2 * 2 * 64 * 32];   // 16 KB
  const int tid = threadIdx.x;
  const int cpx = gridDim.x >> 3;
  const int nid = (blockIdx.x & 7) * cpx + (blockIdx.x >> 3);
  const int nbx = N >> 6;
  const int by = nid / nbx, bx = nid - by * nbx;
  const int m0 = by * 128, n0 = bx * 64;
  const int w = tid >> 6, l = tid & 63;
  const int wm = (w >> 1) * 64, wn = (w & 1) * 32;
  const int lr = l & 15, lg = l >> 4;
  const int srow = tid >> 2;                 // 0..63
  const int scol_lin = (tid & 3) * 8;
  const int scol_e = scol_lin ^ swz(srow);
  const int NT = K >> 6;

  f32x4 acc[4][2];
#pragma unroll
  for (int i = 0; i < 4; i++)
#pragma unroll
    for (int j = 0; j < 2; j++) acc[i][j] = (f32x4){0.f, 0.f, 0.f, 0.f};

  auto stage = [&](int buf, int kt) {
#pragma unroll
    for (int r = 0; r < 2; r++)
#pragma unroll
      for (int cb = 0; cb < 2; cb++)
        gload_lds16(A + (size_t)(m0 + r * 64 + srow) * K + kt * 64 + cb * 32 + scol_e,
                    &As[((buf * 2 + cb) * 128 + r * 64 + srow) * 32 + scol_lin]);
#pragma unroll
    for (int cb = 0; cb < 2; cb++)
      gload_lds16(Bt + (size_t)(n0 + srow) * K + kt * 64 + cb * 32 + scol_e,
                  &Bs[((buf * 2 + cb) * 64 + srow) * 32 + scol_lin]);
  };

  stage(0, 0);
  asm volatile("s_waitcnt vmcnt(0)" ::: "memory");
  __builtin_amdgcn_s_barrier();

  const int cswz = swz(lr);
  const int aBase = (wm + lr) * 32 + ((lg * 8) ^ cswz);
  const int bBase = (wn + lr) * 32 + ((lg * 8) ^ cswz);

  int cur = 0;
#pragma unroll 1
  for (int t = 0; t < NT; t++) {
    if (t + 1 < NT) stage(cur ^ 1, t + 1);
    bf16x8 a[4][2], b[2][2];
#pragma unroll
    for (int i = 0; i < 4; i++)
#pragma unroll
      for (int kk = 0; kk < 2; kk++)
        a[i][kk] = *reinterpret_cast<const bf16x8*>(&As[(cur * 2 + kk) * 4096 + i * 512 + aBase]);
#pragma unroll
    for (int j = 0; j < 2; j++)
#pragma unroll
      for (int kk = 0; kk < 2; kk++)
        b[j][kk] = *reinterpret_cast<const bf16x8*>(&Bs[(cur * 2 + kk) * 2048 + j * 512 + bBase]);
    __builtin_amdgcn_s_setprio(1);
#pragma unroll
    for (int i = 0; i < 4; i++)
#pragma unroll
      for (int j = 0; j < 2; j++)
#pragma unroll
        for (int kk = 0; kk < 2; kk++)
          acc[i][j] = MFMA16(a[i][kk], b[j][kk], acc[i][j]);
    __builtin_amdgcn_s_setprio(0);
    asm volatile("s_waitcnt vmcnt(0)" ::: "memory");
    __builtin_amdgcn_s_barrier();
    cur ^= 1;
  }

#pragma unroll
  for (int i = 0; i < 4; i++) {
    int row = m0 + wm + i * 16 + lg * 4;
#pragma unroll
    for (int j = 0; j < 2; j++) {
      int col = n0 + wn + j * 16 + lr;
      float bsv = bias[col];
#pragma unroll
      for (int r = 0; r < 4; r++)
        storev(&C[(size_t)(row + r) * N + col], acc[i][j][r] + bsv);
    }
  }
}

// ---------------- windowed flash attention ----------------

__global__ __launch_bounds__(256) void attn_kernel(const unsigned short* __restrict__ qkv,
                                                   unsigned short* __restrict__ attnb) {
  __shared__ unsigned short Ks[64 * 72];
  __shared__ unsigned short Vt[64 * 72];
  __shared__ unsigned short Ps[4][16 * 72];

  const int tid = threadIdx.x;
  const int i0 = blockIdx.x * 64;
  const int h = blockIdx.y;
  const int b = blockIdx.z;
  const int w = tid >> 6, l = tid & 63;
  const int lr = l & 15, lg = l >> 4;
  const size_t rowb = (size_t)b * S_LEN;

  const unsigned short* qptr = qkv + (rowb + i0 + w * 16 + lr) * NQKV + h * HDIM;
  bf16x8 qa[2];
  qa[0] = *reinterpret_cast<const bf16x8*>(qptr + lg * 8);
  qa[1] = *reinterpret_cast<const bf16x8*>(qptr + 32 + lg * 8);

  f32x4 accO[4];
#pragma unroll
  for (int f = 0; f < 4; f++) accO[f] = (f32x4){0.f, 0.f, 0.f, 0.f};
  float Mv[4], Lv[4];
#pragma unroll
  for (int r = 0; r < 4; r++) { Mv[r] = -1e30f; Lv[r] = 0.f; }

  for (int c = 0; c < 5; c++) {
    int j0c = i0 - WINSZ + c * 64;
    if (j0c + 63 < 0) continue;
    __syncthreads();
    {
      int d4 = (tid & 15) * 4;
      int jl0 = tid >> 4;
#pragma unroll
      for (int it = 0; it < 4; it++) {
        int jl = jl0 + it * 16;
        int jg = j0c + jl;
        us4 kv = (us4){0, 0, 0, 0}, vv = (us4){0, 0, 0, 0};
        if (jg >= 0) {
          const unsigned short* kp = qkv + (rowb + jg) * NQKV + DMODEL + h * HDIM + d4;
          kv = *reinterpret_cast<const us4*>(kp);
          vv = *reinterpret_cast<const us4*>(kp + DMODEL);
        }
        *reinterpret_cast<us4*>(&Ks[jl * 72 + d4]) = kv;
        Vt[(d4 + 0) * 72 + jl] = vv[0];
        Vt[(d4 + 1) * 72 + jl] = vv[1];
        Vt[(d4 + 2) * 72 + jl] = vv[2];
        Vt[(d4 + 3) * 72 + jl] = vv[3];
      }
    }
    __syncthreads();

    f32x4 sa[4];
#pragma unroll
    for (int f = 0; f < 4; f++) sa[f] = (f32x4){0.f, 0.f, 0.f, 0.f};
#pragma unroll
    for (int f = 0; f < 4; f++) {
      bf16x8 k0v = *reinterpret_cast<const bf16x8*>(&Ks[(f * 16 + lr) * 72 + lg * 8]);
      bf16x8 k1v = *reinterpret_cast<const bf16x8*>(&Ks[(f * 16 + lr) * 72 + 32 + lg * 8]);
      sa[f] = MFMA16(qa[0], k0v, sa[f]);
      sa[f] = MFMA16(qa[1], k1v, sa[f]);
    }
#pragma unroll
    for (int f = 0; f < 4; f++) {
      int jg = j0c + f * 16 + lr;
#pragma unroll
      for (int r = 0; r < 4; r++) {
        int irow = i0 + w * 16 + lg * 4 + r;
        float s = sa[f][r] * 0.125f;
        bool ok = (jg >= 0) && (jg <= irow) && (jg >= irow - WINSZ);
        sa[f][r] = ok ? s : -1e30f;
      }
    }
    float pm[4];
#pragma unroll
    for (int r = 0; r < 4; r++) {
      float m = fmaxf(fmaxf(sa[0][r], sa[1][r]), fmaxf(sa[2][r], sa[3][r]));
#pragma unroll
      for (int off = 1; off < 16; off <<= 1) m = fmaxf(m, __shfl_xor(m, off));
      pm[r] = m;
    }
#pragma unroll
    for (int r = 0; r < 4; r++) {
      float Mn = fmaxf(Mv[r], pm[r]);
      float sc = __expf(Mv[r] - Mn);
      Mv[r] = Mn;
      Lv[r] *= sc;
#pragma unroll
      for (int f = 0; f < 4; f++) accO[f][r] *= sc;
    }
    float rs[4] = {0.f, 0.f, 0.f, 0.f};
#pragma unroll
    for (int f = 0; f < 4; f++) {
#pragma unroll
      for (int r = 0; r < 4; r++) {
        float p = __expf(sa[f][r] - Mv[r]);
        rs[r] += p;
        Ps[w][(lg * 4 + r) * 72 + f * 16 + lr] = f2b(p);
      }
    }
#pragma unroll
    for (int r = 0; r < 4; r++) {
      float s = rs[r];
#pragma unroll
      for (int off = 1; off < 16; off <<= 1) s += __shfl_xor(s, off);
      Lv[r] += s;
    }
    bf16x8 pa0 = *reinterpret_cast<const bf16x8*>(&Ps[w][lr * 72 + lg * 8]);
    bf16x8 pa1 = *reinterpret_cast<const bf16x8*>(&Ps[w][lr * 72 + 32 + lg * 8]);
#pragma unroll
    for (int f = 0; f < 4; f++) {
      bf16x8 v0 = *reinterpret_cast<const bf16x8*>(&Vt[(f * 16 + lr) * 72 + lg * 8]);
      bf16x8 v1 = *reinterpret_cast<const bf16x8*>(&Vt[(f * 16 + lr) * 72 + 32 + lg * 8]);
      accO[f] = MFMA16(pa0, v0, accO[f]);
      accO[f] = MFMA16(pa1, v1, accO[f]);
    }
  }

#pragma unroll
  for (int f = 0; f < 4; f++) {
#pragma unroll
    for (int r = 0; r < 4; r++) {
      float o = accO[f][r] / Lv[r];
      int row = i0 + w * 16 + lg * 4 + r;
      attnb[(rowb + row) * DMODEL + h * HDIM + f * 16 + lr] = f2b(o);
    }
  }
}

// ---------------- launch ----------------

extern "C" void kernel_launch(void* const* d_in, const int* in_sizes, int n_in,
                              void* d_out, int out_size, void* d_ws, size_t ws_size,
                              hipStream_t stream) {
  const float* x = (const float*)d_in[0];
  const float* Wq = (const float*)d_in[1];
  const float* bq = (const float*)d_in[2];
  const float* Wk = (const float*)d_in[3];
  const float* bk = (const float*)d_in[4];
  const float* Wv = (const float*)d_in[5];
  const float* bv = (const float*)d_in[6];
  const float* Wo = (const float*)d_in[7];
  const float* bo = (const float*)d_in[8];
  float* out = (float*)d_out;

  unsigned short* xb = (unsigned short*)d_ws;                       // 4096*1024
  unsigned short* WqkvT = xb + (size_t)MROWS * DMODEL;              // 3*1024*1024
  unsigned short* WoT = WqkvT + (size_t)3 * DMODEL * DMODEL;        // 1024*1024
  unsigned short* QKV = WoT + (size_t)DMODEL * DMODEL;              // 4096*3072
  unsigned short* attnb = QKV + (size_t)MROWS * NQKV;               // 4096*1024
  float* bqkv = (float*)(attnb + (size_t)MROWS * DMODEL);           // 3072 f32

  cast_x_kernel<<<4096, 256, 0, stream>>>(x, xb);
  transpose_cast4_kernel<<<dim3(32, 32, 4), dim3(32, 8), 0, stream>>>(
      Wq, Wk, Wv, Wo,
      WqkvT, WqkvT + (size_t)DMODEL * DMODEL, WqkvT + (size_t)2 * DMODEL * DMODEL, WoT);
  pack_bias_kernel<<<4, 256, 0, stream>>>(bq, bk, bv, bqkv);

  gemm8p_kernel<<<(NQKV / 256) * (MROWS / 256), 512, 0, stream>>>(
      xb, WqkvT, bqkv, QKV, NQKV, DMODEL);

  attn_kernel<<<dim3(S_LEN / 64, NHEAD, 2), 256, 0, stream>>>(QKV, attnb);

  gemm2p_kernel<float><<<(DMODEL / 64) * (MROWS / 128), 256, 0, stream>>>(
      attnb, WoT, bo, out, DMODEL, DMODEL);
}

// Round 5
// 97.811 us; speedup vs baseline: 1.2653x; 1.0703x over previous
//
#include <hip/hip_runtime.h>
#include <stdint.h>
#include <stddef.h>

#define S_LEN 2048
#define DMODEL 1024
#define NHEAD 16
#define HDIM 64
#define WINSZ 256
#define MROWS 4096
#define NQKV 3072

typedef __bf16 bf16x8 __attribute__((ext_vector_type(8)));
typedef float f32x4 __attribute__((ext_vector_type(4)));
typedef unsigned short us4 __attribute__((ext_vector_type(4)));
typedef unsigned short us8 __attribute__((ext_vector_type(8)));

#define MFMA16(a, b, c) __builtin_amdgcn_mfma_f32_16x16x32_bf16((a), (b), (c), 0, 0, 0)

__device__ __forceinline__ unsigned short f2b(float f) {
  union { float f; unsigned u; } v; v.f = f;
  unsigned u = v.u;
  unsigned r = (u + 0x7FFFu + ((u >> 16) & 1u)) >> 16;
  return (unsigned short)r;
}
__device__ __forceinline__ void storev(float* p, float v) { *p = v; }
__device__ __forceinline__ void storev(unsigned short* p, float v) { *p = f2b(v); }

__device__ __forceinline__ void gload_lds16(const unsigned short* g, unsigned short* l) {
  __builtin_amdgcn_global_load_lds(
      (const __attribute__((address_space(1))) unsigned int*)g,
      (__attribute__((address_space(3))) unsigned int*)l, 16, 0, 0);
}

// 2-bit LDS swizzle for 32-elem (64B) rows: col bits {3,4} ^= row bits {2,1}.
__device__ __forceinline__ int swz(int row) {
  return (((row >> 1) & 1) << 4) | (((row >> 2) & 1) << 3);
}

// ---------------- fused prep kernel ----------------
// blocks [0,4096): cast x -> bf16; [4096,8192): transpose+cast 4 weights;
// [8192,8196): pack qkv bias.

__global__ void prep_kernel(const float* __restrict__ x,
                            const float* __restrict__ Wq, const float* __restrict__ Wk,
                            const float* __restrict__ Wv, const float* __restrict__ Wo,
                            const float* __restrict__ bq, const float* __restrict__ bk,
                            const float* __restrict__ bv,
                            unsigned short* __restrict__ xb, unsigned short* __restrict__ WqkvT,
                            unsigned short* __restrict__ WoT, float* __restrict__ bqkv) {
  __shared__ float tile[32][33];
  const int bid = blockIdx.x;
  const int tid = threadIdx.x;
  if (bid < 4096) {
    int i = (bid * 256 + tid) * 4;
    float4 v = *reinterpret_cast<const float4*>(x + i);
    us4 o;
    o[0] = f2b(v.x); o[1] = f2b(v.y); o[2] = f2b(v.z); o[3] = f2b(v.w);
    *reinterpret_cast<us4*>(xb + i) = o;
  } else if (bid < 8192) {
    int z = (bid - 4096) >> 10;
    int rem = (bid - 4096) & 1023;
    int bx = rem & 31, by = rem >> 5;
    const float* W = (z == 0) ? Wq : (z == 1) ? Wk : (z == 2) ? Wv : Wo;
    unsigned short* Wt = (z == 3) ? WoT : WqkvT + (size_t)z * DMODEL * DMODEL;
    int n0 = bx * 32, k0 = by * 32;
    int tx = tid & 31, ty = tid >> 5;  // 32 x 8
#pragma unroll
    for (int i = 0; i < 32; i += 8)
      tile[ty + i][tx] = W[(size_t)(k0 + ty + i) * DMODEL + n0 + tx];
    __syncthreads();
#pragma unroll
    for (int i = 0; i < 32; i += 8)
      Wt[(size_t)(n0 + ty + i) * DMODEL + k0 + tx] = f2b(tile[tx][ty + i]);
  } else {
    int i = (bid - 8192) * 256 + tid;
    if (i < DMODEL) {
      bqkv[i] = bq[i];
      bqkv[DMODEL + i] = bk[i];
      bqkv[2 * DMODEL + i] = bv[i];
    }
  }
}

// ---------------- 8-phase 256x192 GEMM (QKV projection) ----------------
// 512 threads = 8 waves (2M x 4N), wave tile 128x48, BK=64,
// LDS: As [dbuf2][kk2][256][32] = 64KB, Bs [dbuf2][h3][kk2][64][32] = 48KB.
// 2-bit swizzle, counted vmcnt(1), setprio, chunked XCD swizzle. Grid 256 = full fill.

__global__ __launch_bounds__(512, 2) void gemm8p_kernel(
    const unsigned short* __restrict__ A, const unsigned short* __restrict__ Bt,
    const float* __restrict__ bias, unsigned short* __restrict__ C, int N, int K) {
  __shared__ unsigned short As[2 * 2 * 256 * 32];      // 65536 elems
  __shared__ unsigned short Bs[2 * 3 * 2 * 64 * 32];   // 24576 elems
  const int tid = threadIdx.x;
  const int cpx = gridDim.x >> 3;
  const int nid = (blockIdx.x & 7) * cpx + (blockIdx.x >> 3);
  const int nbx = N / 192;
  const int by = nid / nbx, bx = nid - by * nbx;
  const int m0 = by * 256, n0 = bx * 192;
  const int wid = tid >> 6, l = tid & 63;
  const int wm = wid >> 2, wn = wid & 3;
  const int lr = l & 15, lg = l >> 4;
  // A staging: 128 rows x 32 cols per gload round
  const int srow = tid >> 2;                 // 0..127
  const int scol_lin = (tid & 3) * 8;
  const int scol_e = scol_lin ^ swz(srow);
  // B staging: one call = 64 rows x 64 cols, layout [kk][64][32]
  const int srowB = (tid & 255) >> 2;        // 0..63
  const int kkB = tid >> 8;                  // 0..1
  const int scolB8 = (tid & 3) * 8;
  const int scolB_e = scolB8 ^ swz(srowB);
  const int NT = K >> 6;

  f32x4 acc[8][3];
#pragma unroll
  for (int i = 0; i < 8; i++)
#pragma unroll
    for (int j = 0; j < 3; j++) acc[i][j] = (f32x4){0.f, 0.f, 0.f, 0.f};

  auto stA = [&](int q, int h, int kt) {
#pragma unroll
    for (int cb = 0; cb < 2; cb++)
      gload_lds16(A + (size_t)(m0 + h * 128 + srow) * K + kt * 64 + cb * 32 + scol_e,
                  &As[((q * 2 + cb) * 256 + h * 128 + srow) * 32 + scol_lin]);
  };
  auto stB = [&](int q, int h, int kt) {
    gload_lds16(Bt + (size_t)(n0 + h * 64 + srowB) * K + kt * 64 + kkB * 32 + scolB_e,
                &Bs[((q * 3 + h) * 2 + kkB) * 2048 + srowB * 32 + scolB8]);
  };

  // prologue: tile0 (B0,B1,B2,A0,A1) + B0(tile1); drain all but newest.
  stB(0, 0, 0); stB(0, 1, 0); stB(0, 2, 0); stA(0, 0, 0); stA(0, 1, 0); stB(1, 0, 1);
  asm volatile("s_waitcnt vmcnt(1)" ::: "memory");
  __builtin_amdgcn_s_barrier();

  bf16x8 a[4][2], b01[2][2], b2[2];
  const int cswz = swz(lr);
  const int aBase = (wm * 128 + lr) * 32 + ((lg * 8) ^ cswz);
  int bOff[3];
#pragma unroll
  for (int j = 0; j < 3; j++) {
    int base = wn * 48 + j * 16;
    bOff[j] = (base >> 6) * 4096 + ((base & 63) + lr) * 32 + ((lg * 8) ^ cswz);
  }

#pragma unroll 1
  for (int t = 0; t < NT; t++) {
    const int p = t & 1, q = p ^ 1;
    const int ap = p * 16384, bp = p * 12288;

    // phase 0: read a(0..3)+b(0..1); stage B1,B2(t+1); MFMA i0-3 x j0-1
#pragma unroll
    for (int i = 0; i < 4; i++)
#pragma unroll
      for (int kk = 0; kk < 2; kk++)
        a[i][kk] = *reinterpret_cast<const bf16x8*>(&As[ap + kk * 8192 + i * 512 + aBase]);
#pragma unroll
    for (int j = 0; j < 2; j++)
#pragma unroll
      for (int kk = 0; kk < 2; kk++)
        b01[j][kk] = *reinterpret_cast<const bf16x8*>(&Bs[bp + kk * 2048 + bOff[j]]);
    if (t + 1 < NT) { stB(q, 1, t + 1); stB(q, 2, t + 1); }
    __builtin_amdgcn_s_barrier();
    __builtin_amdgcn_s_setprio(1);
#pragma unroll
    for (int i = 0; i < 4; i++)
#pragma unroll
      for (int j = 0; j < 2; j++)
#pragma unroll
        for (int kk = 0; kk < 2; kk++)
          acc[i][j] = MFMA16(a[i][kk], b01[j][kk], acc[i][j]);
    __builtin_amdgcn_s_setprio(0);
    __builtin_amdgcn_s_barrier();

    // phase 1: read b2; stage A0(t+1); MFMA i0-3 x j2
#pragma unroll
    for (int kk = 0; kk < 2; kk++)
      b2[kk] = *reinterpret_cast<const bf16x8*>(&Bs[bp + kk * 2048 + bOff[2]]);
    if (t + 1 < NT) stA(q, 0, t + 1);
    __builtin_amdgcn_s_barrier();
    __builtin_amdgcn_s_setprio(1);
#pragma unroll
    for (int i = 0; i < 4; i++)
#pragma unroll
      for (int kk = 0; kk < 2; kk++)
        acc[i][2] = MFMA16(a[i][kk], b2[kk], acc[i][2]);
    __builtin_amdgcn_s_setprio(0);
    __builtin_amdgcn_s_barrier();

    // phase 2: read a(4..7); stage A1(t+1); MFMA i4-7 x j0-1
#pragma unroll
    for (int i = 0; i < 4; i++)
#pragma unroll
      for (int kk = 0; kk < 2; kk++)
        a[i][kk] = *reinterpret_cast<const bf16x8*>(&As[ap + kk * 8192 + (i + 4) * 512 + aBase]);
    if (t + 1 < NT) stA(q, 1, t + 1);
    __builtin_amdgcn_s_barrier();
    __builtin_amdgcn_s_setprio(1);
#pragma unroll
    for (int i = 0; i < 4; i++)
#pragma unroll
      for (int j = 0; j < 2; j++)
#pragma unroll
        for (int kk = 0; kk < 2; kk++)
          acc[i + 4][j] = MFMA16(a[i][kk], b01[j][kk], acc[i + 4][j]);
    __builtin_amdgcn_s_setprio(0);
    __builtin_amdgcn_s_barrier();

    // phase 3: stage B0(t+2); MFMA i4-7 x j2; counted vmcnt
    if (t + 2 < NT) stB(p, 0, t + 2);
    __builtin_amdgcn_s_barrier();
    __builtin_amdgcn_s_setprio(1);
#pragma unroll
    for (int i = 0; i < 4; i++)
#pragma unroll
      for (int kk = 0; kk < 2; kk++)
        acc[i + 4][2] = MFMA16(a[i][kk], b2[kk], acc[i + 4][2]);
    __builtin_amdgcn_s_setprio(0);
    if (t + 2 < NT) {
      asm volatile("s_waitcnt vmcnt(1)" ::: "memory");
    } else {
      asm volatile("s_waitcnt vmcnt(0)" ::: "memory");
    }
    __builtin_amdgcn_s_barrier();
  }

#pragma unroll
  for (int i = 0; i < 8; i++) {
    int row = m0 + wm * 128 + i * 16 + lg * 4;
#pragma unroll
    for (int j = 0; j < 3; j++) {
      int col = n0 + wn * 48 + j * 16 + lr;
      float bsv = bias[col];
#pragma unroll
      for (int r = 0; r < 4; r++)
        C[(size_t)(row + r) * N + col] = f2b(acc[i][j][r] + bsv);
    }
  }
}

// ---------------- 2-phase 128x64 GEMM (output projection) ----------------

template <typename OutT>
__global__ __launch_bounds__(256, 3) void gemm2p_kernel(
    const unsigned short* __restrict__ A, const unsigned short* __restrict__ Bt,
    const float* __restrict__ bias, OutT* __restrict__ C, int N, int K) {
  __shared__ unsigned short As[2 * 2 * 128 * 32];  // 32 KB
  __shared__ unsigned short Bs[2 * 2 * 64 * 32];   // 16 KB
  const int tid = threadIdx.x;
  const int cpx = gridDim.x >> 3;
  const int nid = (blockIdx.x & 7) * cpx + (blockIdx.x >> 3);
  const int nbx = N >> 6;
  const int by = nid / nbx, bx = nid - by * nbx;
  const int m0 = by * 128, n0 = bx * 64;
  const int w = tid >> 6, l = tid & 63;
  const int wm = (w >> 1) * 64, wn = (w & 1) * 32;
  const int lr = l & 15, lg = l >> 4;
  const int srow = tid >> 2;                 // 0..63
  const int scol_lin = (tid & 3) * 8;
  const int scol_e = scol_lin ^ swz(srow);
  const int NT = K >> 6;

  f32x4 acc[4][2];
#pragma unroll
  for (int i = 0; i < 4; i++)
#pragma unroll
    for (int j = 0; j < 2; j++) acc[i][j] = (f32x4){0.f, 0.f, 0.f, 0.f};

  auto stage = [&](int buf, int kt) {
#pragma unroll
    for (int r = 0; r < 2; r++)
#pragma unroll
      for (int cb = 0; cb < 2; cb++)
        gload_lds16(A + (size_t)(m0 + r * 64 + srow) * K + kt * 64 + cb * 32 + scol_e,
                    &As[((buf * 2 + cb) * 128 + r * 64 + srow) * 32 + scol_lin]);
#pragma unroll
    for (int cb = 0; cb < 2; cb++)
      gload_lds16(Bt + (size_t)(n0 + srow) * K + kt * 64 + cb * 32 + scol_e,
                  &Bs[((buf * 2 + cb) * 64 + srow) * 32 + scol_lin]);
  };

  stage(0, 0);
  asm volatile("s_waitcnt vmcnt(0)" ::: "memory");
  __builtin_amdgcn_s_barrier();

  const int cswz = swz(lr);
  const int aBase = (wm + lr) * 32 + ((lg * 8) ^ cswz);
  const int bBase = (wn + lr) * 32 + ((lg * 8) ^ cswz);

  int cur = 0;
#pragma unroll 1
  for (int t = 0; t < NT; t++) {
    if (t + 1 < NT) stage(cur ^ 1, t + 1);
    bf16x8 a[4][2], b[2][2];
#pragma unroll
    for (int i = 0; i < 4; i++)
#pragma unroll
      for (int kk = 0; kk < 2; kk++)
        a[i][kk] = *reinterpret_cast<const bf16x8*>(&As[(cur * 2 + kk) * 4096 + i * 512 + aBase]);
#pragma unroll
    for (int j = 0; j < 2; j++)
#pragma unroll
      for (int kk = 0; kk < 2; kk++)
        b[j][kk] = *reinterpret_cast<const bf16x8*>(&Bs[(cur * 2 + kk) * 2048 + j * 512 + bBase]);
    __builtin_amdgcn_s_setprio(1);
#pragma unroll
    for (int i = 0; i < 4; i++)
#pragma unroll
      for (int j = 0; j < 2; j++)
#pragma unroll
        for (int kk = 0; kk < 2; kk++)
          acc[i][j] = MFMA16(a[i][kk], b[j][kk], acc[i][j]);
    __builtin_amdgcn_s_setprio(0);
    asm volatile("s_waitcnt vmcnt(0)" ::: "memory");
    __builtin_amdgcn_s_barrier();
    cur ^= 1;
  }

#pragma unroll
  for (int i = 0; i < 4; i++) {
    int row = m0 + wm + i * 16 + lg * 4;
#pragma unroll
    for (int j = 0; j < 2; j++) {
      int col = n0 + wn + j * 16 + lr;
      float bsv = bias[col];
#pragma unroll
      for (int r = 0; r < 4; r++)
        storev(&C[(size_t)(row + r) * N + col], acc[i][j][r] + bsv);
    }
  }
}

// ---------------- windowed flash attention ----------------

__global__ __launch_bounds__(256) void attn_kernel(const unsigned short* __restrict__ qkv,
                                                   unsigned short* __restrict__ attnb) {
  __shared__ unsigned short Ks[64 * 72];
  __shared__ unsigned short Vt[64 * 72];
  __shared__ unsigned short Ps[4][16 * 72];

  const int tid = threadIdx.x;
  const int i0 = blockIdx.x * 64;
  const int h = blockIdx.y;
  const int b = blockIdx.z;
  const int w = tid >> 6, l = tid & 63;
  const int lr = l & 15, lg = l >> 4;
  const size_t rowb = (size_t)b * S_LEN;

  const unsigned short* qptr = qkv + (rowb + i0 + w * 16 + lr) * NQKV + h * HDIM;
  bf16x8 qa[2];
  qa[0] = *reinterpret_cast<const bf16x8*>(qptr + lg * 8);
  qa[1] = *reinterpret_cast<const bf16x8*>(qptr + 32 + lg * 8);

  f32x4 accO[4];
#pragma unroll
  for (int f = 0; f < 4; f++) accO[f] = (f32x4){0.f, 0.f, 0.f, 0.f};
  float Mv[4], Lv[4];
#pragma unroll
  for (int r = 0; r < 4; r++) { Mv[r] = -1e30f; Lv[r] = 0.f; }

  for (int c = 0; c < 5; c++) {
    int j0c = i0 - WINSZ + c * 64;
    if (j0c + 63 < 0) continue;
    __syncthreads();
    {
      int d8 = (tid & 7) * 8;
      int jl0 = tid >> 3;  // 0..31
#pragma unroll
      for (int it = 0; it < 2; it++) {
        int jl = jl0 + it * 32;
        int jg = j0c + jl;
        us8 kv = (us8){0, 0, 0, 0, 0, 0, 0, 0}, vv = (us8){0, 0, 0, 0, 0, 0, 0, 0};
        if (jg >= 0) {
          const unsigned short* kp = qkv + (rowb + jg) * NQKV + DMODEL + h * HDIM + d8;
          kv = *reinterpret_cast<const us8*>(kp);
          vv = *reinterpret_cast<const us8*>(kp + DMODEL);
        }
        *reinterpret_cast<us8*>(&Ks[jl * 72 + d8]) = kv;
#pragma unroll
        for (int e = 0; e < 8; e++) Vt[(d8 + e) * 72 + jl] = vv[e];
      }
    }
    __syncthreads();

    f32x4 sa[4];
#pragma unroll
    for (int f = 0; f < 4; f++) sa[f] = (f32x4){0.f, 0.f, 0.f, 0.f};
#pragma unroll
    for (int f = 0; f < 4; f++) {
      bf16x8 k0v = *reinterpret_cast<const bf16x8*>(&Ks[(f * 16 + lr) * 72 + lg * 8]);
      bf16x8 k1v = *reinterpret_cast<const bf16x8*>(&Ks[(f * 16 + lr) * 72 + 32 + lg * 8]);
      sa[f] = MFMA16(qa[0], k0v, sa[f]);
      sa[f] = MFMA16(qa[1], k1v, sa[f]);
    }
#pragma unroll
    for (int f = 0; f < 4; f++) {
      int jg = j0c + f * 16 + lr;
#pragma unroll
      for (int r = 0; r < 4; r++) {
        int irow = i0 + w * 16 + lg * 4 + r;
        float s = sa[f][r] * 0.125f;
        bool ok = (jg >= 0) && (jg <= irow) && (jg >= irow - WINSZ);
        sa[f][r] = ok ? s : -1e30f;
      }
    }
    float pm[4];
#pragma unroll
    for (int r = 0; r < 4; r++) {
      float m = fmaxf(fmaxf(sa[0][r], sa[1][r]), fmaxf(sa[2][r], sa[3][r]));
#pragma unroll
      for (int off = 1; off < 16; off <<= 1) m = fmaxf(m, __shfl_xor(m, off));
      pm[r] = m;
    }
#pragma unroll
    for (int r = 0; r < 4; r++) {
      float Mn = fmaxf(Mv[r], pm[r]);
      float sc = __expf(Mv[r] - Mn);
      Mv[r] = Mn;
      Lv[r] *= sc;
#pragma unroll
      for (int f = 0; f < 4; f++) accO[f][r] *= sc;
    }
    float rs[4] = {0.f, 0.f, 0.f, 0.f};
#pragma unroll
    for (int f = 0; f < 4; f++) {
#pragma unroll
      for (int r = 0; r < 4; r++) {
        float p = __expf(sa[f][r] - Mv[r]);
        rs[r] += p;
        Ps[w][(lg * 4 + r) * 72 + f * 16 + lr] = f2b(p);
      }
    }
#pragma unroll
    for (int r = 0; r < 4; r++) {
      float s = rs[r];
#pragma unroll
      for (int off = 1; off < 16; off <<= 1) s += __shfl_xor(s, off);
      Lv[r] += s;
    }
    bf16x8 pa0 = *reinterpret_cast<const bf16x8*>(&Ps[w][lr * 72 + lg * 8]);
    bf16x8 pa1 = *reinterpret_cast<const bf16x8*>(&Ps[w][lr * 72 + 32 + lg * 8]);
#pragma unroll
    for (int f = 0; f < 4; f++) {
      bf16x8 v0 = *reinterpret_cast<const bf16x8*>(&Vt[(f * 16 + lr) * 72 + lg * 8]);
      bf16x8 v1 = *reinterpret_cast<const bf16x8*>(&Vt[(f * 16 + lr) * 72 + 32 + lg * 8]);
      accO[f] = MFMA16(pa0, v0, accO[f]);
      accO[f] = MFMA16(pa1, v1, accO[f]);
    }
  }

#pragma unroll
  for (int f = 0; f < 4; f++) {
#pragma unroll
    for (int r = 0; r < 4; r++) {
      float o = accO[f][r] / Lv[r];
      int row = i0 + w * 16 + lg * 4 + r;
      attnb[(rowb + row) * DMODEL + h * HDIM + f * 16 + lr] = f2b(o);
    }
  }
}

// ---------------- launch ----------------

extern "C" void kernel_launch(void* const* d_in, const int* in_sizes, int n_in,
                              void* d_out, int out_size, void* d_ws, size_t ws_size,
                              hipStream_t stream) {
  const float* x = (const float*)d_in[0];
  const float* Wq = (const float*)d_in[1];
  const float* bq = (const float*)d_in[2];
  const float* Wk = (const float*)d_in[3];
  const float* bk = (const float*)d_in[4];
  const float* Wv = (const float*)d_in[5];
  const float* bv = (const float*)d_in[6];
  const float* Wo = (const float*)d_in[7];
  const float* bo = (const float*)d_in[8];
  float* out = (float*)d_out;

  unsigned short* xb = (unsigned short*)d_ws;                       // 4096*1024
  unsigned short* WqkvT = xb + (size_t)MROWS * DMODEL;              // 3*1024*1024
  unsigned short* WoT = WqkvT + (size_t)3 * DMODEL * DMODEL;        // 1024*1024
  unsigned short* QKV = WoT + (size_t)DMODEL * DMODEL;              // 4096*3072
  unsigned short* attnb = QKV + (size_t)MROWS * NQKV;               // 4096*1024
  float* bqkv = (float*)(attnb + (size_t)MROWS * DMODEL);           // 3072 f32

  prep_kernel<<<8196, 256, 0, stream>>>(x, Wq, Wk, Wv, Wo, bq, bk, bv,
                                        xb, WqkvT, WoT, bqkv);

  gemm8p_kernel<<<(NQKV / 192) * (MROWS / 256), 512, 0, stream>>>(
      xb, WqkvT, bqkv, QKV, NQKV, DMODEL);

  attn_kernel<<<dim3(S_LEN / 64, NHEAD, 2), 256, 0, stream>>>(QKV, attnb);

  gemm2p_kernel<float><<<(DMODEL / 64) * (MROWS / 128), 256, 0, stream>>>(
      attnb, WoT, bo, out, DMODEL, DMODEL);
}